// Round 1
// baseline (327.522 us; speedup 1.0000x reference)
//
#include <hip/hip_runtime.h>
#include <hip/hip_bf16.h>
#include <stdint.h>

#define B_ROWS 16384
#define D_K    2048
#define C_COLS 1000
#define C_PAD  1024
#define EPS_D2 1e-12f

typedef __attribute__((ext_vector_type(8))) short bf16x8;
typedef __attribute__((ext_vector_type(4))) float f32x4;

__device__ __forceinline__ unsigned short f2bf_rne(float f) {
    union { float f; uint32_t u; } a; a.f = f;
    uint32_t u = a.u;
    uint32_t r = (u + 0x7FFFu + ((u >> 16) & 1u)) >> 16;
    return (unsigned short)r;
}

__device__ __forceinline__ void async16(void* lds, const void* g) {
    __builtin_amdgcn_global_load_lds(
        (const __attribute__((address_space(1))) unsigned int*)g,
        (__attribute__((address_space(3))) unsigned int*)lds,
        16, 0, 0);
}

// One block per row: convert fp32 row -> bf16, compute sum of squares (fp32).
// Rows [0, B_ROWS) are x; rows [B_ROWS, B_ROWS+C_PAD) are w (zero-padded past C_COLS).
__global__ void prep_kernel(const float* __restrict__ x, const float* __restrict__ w,
                            __hip_bfloat16* __restrict__ xb, __hip_bfloat16* __restrict__ wb,
                            float* __restrict__ x2, float* __restrict__ w2) {
    const int row = blockIdx.x;
    const int t = threadIdx.x;

    const float* src;
    __hip_bfloat16* dst;
    float* norm_out;
    bool valid;
    if (row < B_ROWS) {
        src = x + (size_t)row * D_K;
        dst = xb + (size_t)row * D_K;
        norm_out = x2 + row;
        valid = true;
    } else {
        int c = row - B_ROWS;
        src = w + (size_t)c * D_K;
        dst = wb + (size_t)c * D_K;
        norm_out = w2 + c;
        valid = (c < C_COLS);
    }

    float4 v0, v1;
    if (valid) {
        const float4* s4 = (const float4*)src;
        v0 = s4[t];          // floats [t*4, t*4+4)
        v1 = s4[t + 256];    // floats [(t+256)*4, ...)
    } else {
        v0 = make_float4(0.f, 0.f, 0.f, 0.f);
        v1 = v0;
    }

    float ss = v0.x*v0.x + v0.y*v0.y + v0.z*v0.z + v0.w*v0.w
             + v1.x*v1.x + v1.y*v1.y + v1.z*v1.z + v1.w*v1.w;

    uint2 p0, p1;
    p0.x = (uint32_t)f2bf_rne(v0.x) | ((uint32_t)f2bf_rne(v0.y) << 16);
    p0.y = (uint32_t)f2bf_rne(v0.z) | ((uint32_t)f2bf_rne(v0.w) << 16);
    p1.x = (uint32_t)f2bf_rne(v1.x) | ((uint32_t)f2bf_rne(v1.y) << 16);
    p1.y = (uint32_t)f2bf_rne(v1.z) | ((uint32_t)f2bf_rne(v1.w) << 16);
    ((uint2*)dst)[t]       = p0;
    ((uint2*)dst)[t + 256] = p1;

    // block reduce ss (4 waves of 64)
    #pragma unroll
    for (int off = 32; off > 0; off >>= 1) ss += __shfl_down(ss, off, 64);
    __shared__ float wsum[4];
    if ((t & 63) == 0) wsum[t >> 6] = ss;
    __syncthreads();
    if (t == 0) *norm_out = wsum[0] + wsum[1] + wsum[2] + wsum[3];
}

// 128x128 tile, BK=32, 256 threads = 4 waves in 2x2, each wave 64x64 via 4x4 MFMA 16x16x32.
__global__ __launch_bounds__(256) void dml_gemm(
    const __hip_bfloat16* __restrict__ A,   // [B_ROWS, D_K] bf16
    const __hip_bfloat16* __restrict__ Bm,  // [C_PAD, D_K] bf16 (row-major by K; padded)
    const float* __restrict__ x2, const float* __restrict__ w2,
    const float* __restrict__ scales, float* __restrict__ out)
{
    __shared__ __align__(16) __hip_bfloat16 lsA[128 * 32];
    __shared__ __align__(16) __hip_bfloat16 lsB[128 * 32];

    const int tid  = threadIdx.x;
    const int wave = tid >> 6;
    const int lane = tid & 63;
    const int m0 = blockIdx.y * 128;
    const int n0 = blockIdx.x * 128;
    const int wm = wave >> 1;
    const int wn = wave & 1;

    // Staging: each wave issues 2 A + 2 B global_load_lds (16B/lane).
    // A-tile row covered by this lane for instr0 (instr1 = +16 rows):
    const int srow = wave * 32 + (lane >> 2);
    const int scol = (lane & 3) * 8;
    const __hip_bfloat16* gA0 = A  + (size_t)(m0 + srow) * D_K + scol;
    const __hip_bfloat16* gA1 = gA0 + (size_t)16 * D_K;
    const __hip_bfloat16* gB0 = Bm + (size_t)(n0 + srow) * D_K + scol;
    const __hip_bfloat16* gB1 = gB0 + (size_t)16 * D_K;
    // LDS dest: row*64B + (lane&3)*16B == wave_base + lane*16 (HW-required contiguous order)
    char* lA0 = (char*)lsA + wave * 32 * 64 + lane * 16;
    char* lA1 = lA0 + 16 * 64;
    char* lB0 = (char*)lsB + wave * 32 * 64 + lane * 16;
    char* lB1 = lB0 + 16 * 64;

    // Fragment read pointers (A: m=lane&15, k-quad=lane>>4; B symmetric since stored [n][k])
    const int fr = lane & 15;
    const int fq = lane >> 4;
    const __hip_bfloat16* fA = lsA + (wm * 64 + fr) * 32 + fq * 8;
    const __hip_bfloat16* fB = lsB + (wn * 64 + fr) * 32 + fq * 8;

    f32x4 acc[4][4] = {};

    for (int k0 = 0; k0 < D_K; k0 += 32) {
        __syncthreads();               // LDS safe to overwrite
        async16(lA0, gA0); async16(lA1, gA1);
        async16(lB0, gB0); async16(lB1, gB1);
        gA0 += 32; gA1 += 32; gB0 += 32; gB1 += 32;
        __syncthreads();               // drains vmcnt -> staged data visible

        bf16x8 a[4], b[4];
        #pragma unroll
        for (int i = 0; i < 4; i++) a[i] = *(const bf16x8*)(fA + i * 16 * 32);
        #pragma unroll
        for (int j = 0; j < 4; j++) b[j] = *(const bf16x8*)(fB + j * 16 * 32);
        #pragma unroll
        for (int i = 0; i < 4; i++)
            #pragma unroll
            for (int j = 0; j < 4; j++)
                acc[i][j] = __builtin_amdgcn_mfma_f32_16x16x32_bf16(a[i], b[j], acc[i][j], 0, 0, 0);
    }

    // Epilogue: d2 = x2 + w2 - 2*cross; out = -s*sqrt(max(d2, eps))
    const float s = scales[0];
    const int colb = n0 + wn * 64 + fr;          // C/D: col = lane&15
    const int rowb = m0 + wm * 64 + fq * 4;      // C/D: row = (lane>>4)*4 + reg

    float xv[4][4];
    #pragma unroll
    for (int i = 0; i < 4; i++)
        #pragma unroll
        for (int r = 0; r < 4; r++)
            xv[i][r] = x2[rowb + i * 16 + r];

    #pragma unroll
    for (int j = 0; j < 4; j++) {
        const int gn = colb + j * 16;
        const bool nok = (gn < C_COLS);
        const float w2v = nok ? w2[gn] : 0.f;
        #pragma unroll
        for (int i = 0; i < 4; i++) {
            const int gm = rowb + i * 16;
            #pragma unroll
            for (int r = 0; r < 4; r++) {
                float d2 = xv[i][r] + w2v - 2.0f * acc[i][j][r];
                d2 = fmaxf(d2, EPS_D2);
                float val = -s * __builtin_sqrtf(d2);
                if (nok) out[(size_t)(gm + r) * C_COLS + gn] = val;
            }
        }
    }
}

extern "C" void kernel_launch(void* const* d_in, const int* in_sizes, int n_in,
                              void* d_out, int out_size, void* d_ws, size_t ws_size,
                              hipStream_t stream) {
    const float* x      = (const float*)d_in[0];
    const float* w      = (const float*)d_in[1];
    const float* scales = (const float*)d_in[2];
    float* out = (float*)d_out;

    char* ws = (char*)d_ws;
    __hip_bfloat16* xb = (__hip_bfloat16*)ws;                                  // 67,108,864 B
    __hip_bfloat16* wb = (__hip_bfloat16*)(ws + (size_t)B_ROWS * D_K * 2);     //  4,194,304 B
    float* x2 = (float*)(ws + (size_t)B_ROWS * D_K * 2 + (size_t)C_PAD * D_K * 2);
    float* w2 = x2 + B_ROWS;

    prep_kernel<<<dim3(B_ROWS + C_PAD), dim3(256), 0, stream>>>(x, w, xb, wb, x2, w2);
    dml_gemm<<<dim3(C_PAD / 128, B_ROWS / 128), dim3(256), 0, stream>>>(xb, wb, x2, w2, scales, out);
}

// Round 2
// 320.116 us; speedup vs baseline: 1.0231x; 1.0231x over previous
//
#include <hip/hip_runtime.h>
#include <hip/hip_bf16.h>
#include <stdint.h>

#define B_ROWS 16384
#define D_K    2048
#define C_COLS 1000
#define C_PAD  1024
#define EPS_D2 1e-12f

typedef __attribute__((ext_vector_type(8))) short bf16x8;
typedef __attribute__((ext_vector_type(4))) float f32x4;

__device__ __forceinline__ unsigned short f2bf_rne(float f) {
    union { float f; uint32_t u; } a; a.f = f;
    uint32_t u = a.u;
    uint32_t r = (u + 0x7FFFu + ((u >> 16) & 1u)) >> 16;
    return (unsigned short)r;
}

__device__ __forceinline__ void async16(void* lds, const void* g) {
    __builtin_amdgcn_global_load_lds(
        (const __attribute__((address_space(1))) unsigned int*)g,
        (__attribute__((address_space(3))) unsigned int*)lds,
        16, 0, 0);
}

// Wave-per-row prep: convert fp32 row -> bf16 (RNE), fp32 sum-of-squares.
// Rows [0,B_ROWS) = x; rows [B_ROWS, B_ROWS+C_PAD) = w (zero-padded past C_COLS).
// 64 lanes x 8 float4 = 2048 floats/row; 8 independent loads in flight per lane.
__global__ __launch_bounds__(256) void prep_kernel(
    const float* __restrict__ x, const float* __restrict__ w,
    __hip_bfloat16* __restrict__ xb, __hip_bfloat16* __restrict__ wb,
    float* __restrict__ x2, float* __restrict__ w2) {
    const int t = threadIdx.x;
    const int wave = t >> 6;
    const int lane = t & 63;
    const int row = blockIdx.x * 4 + wave;

    const float* src;
    __hip_bfloat16* dst;
    float* norm_out;
    bool valid;
    if (row < B_ROWS) {
        src = x + (size_t)row * D_K;
        dst = xb + (size_t)row * D_K;
        norm_out = x2 + row;
        valid = true;
    } else {
        int c = row - B_ROWS;
        src = w + (size_t)c * D_K;
        dst = wb + (size_t)c * D_K;
        norm_out = w2 + c;
        valid = (c < C_COLS);
    }

    float4 v[8];
    if (valid) {
        const float4* s4 = (const float4*)src;
        #pragma unroll
        for (int i = 0; i < 8; i++) v[i] = s4[lane + 64 * i];   // 8 independent 16B loads
    } else {
        #pragma unroll
        for (int i = 0; i < 8; i++) v[i] = make_float4(0.f, 0.f, 0.f, 0.f);
    }

    float ss = 0.f;
    uint2* d2p = (uint2*)dst;
    #pragma unroll
    for (int i = 0; i < 8; i++) {
        ss += v[i].x * v[i].x + v[i].y * v[i].y + v[i].z * v[i].z + v[i].w * v[i].w;
        uint2 p;
        p.x = (uint32_t)f2bf_rne(v[i].x) | ((uint32_t)f2bf_rne(v[i].y) << 16);
        p.y = (uint32_t)f2bf_rne(v[i].z) | ((uint32_t)f2bf_rne(v[i].w) << 16);
        d2p[lane + 64 * i] = p;
    }

    #pragma unroll
    for (int off = 32; off > 0; off >>= 1) ss += __shfl_down(ss, off, 64);
    if (lane == 0 && valid) *norm_out = ss;
}

// 128x128 tile, BK=32, 256 threads = 4 waves in 2x2, each wave 64x64 via 4x4 MFMA 16x16x32.
// XCD-remapped block ids: each XCD owns 16 complete m-tiles -> A-tile L2 reuse.
// XOR-swizzled LDS chunk layout: row r, slot s holds global chunk s^((r>>1)&3)
// -> fragment ds_read_b128 is 2-way (free) instead of 8-way bank-conflicted.
__global__ __launch_bounds__(256) void dml_gemm(
    const __hip_bfloat16* __restrict__ A,   // [B_ROWS, D_K] bf16
    const __hip_bfloat16* __restrict__ Bm,  // [C_PAD, D_K] bf16 (row-major by K; padded)
    const float* __restrict__ x2, const float* __restrict__ w2,
    const float* __restrict__ scales, float* __restrict__ out)
{
    __shared__ __align__(16) __hip_bfloat16 lsA[128 * 32];
    __shared__ __align__(16) __hip_bfloat16 lsB[128 * 32];

    const int tid  = threadIdx.x;
    const int wave = tid >> 6;
    const int lane = tid & 63;

    // XCD-aware remap: dispatch round-robins linear id % 8 across XCDs.
    // Give XCD x the m-tiles [x*16, x*16+16); its 8 n-blocks per m-tile are
    // consecutive j on the same XCD -> A-tile (1 MB working set) hits L2.
    const int id  = blockIdx.y * 8 + blockIdx.x;   // gridDim.x == 8
    const int xcd = id & 7;
    const int j   = id >> 3;                       // 0..127 within XCD
    const int m0  = (xcd * 16 + (j >> 3)) * 128;
    const int n0  = (j & 7) * 128;

    const int wm = wave >> 1;
    const int wn = wave & 1;

    // Staging: lane covers (srow, slot). Global chunk fetched = slot ^ sw(srow)
    // so that LDS dest (forced = wave_base + lane*16) lands the swizzled layout.
    const int srow = wave * 32 + (lane >> 2);
    const int slot = lane & 3;
    const int ssw  = (srow >> 1) & 3;
    const int scol = (slot ^ ssw) * 8;
    const __hip_bfloat16* gA0 = A  + (size_t)(m0 + srow) * D_K + scol;
    const __hip_bfloat16* gA1 = gA0 + (size_t)16 * D_K;   // +16 rows: sw unchanged (16>>1=8, &3==0)
    const __hip_bfloat16* gB0 = Bm + (size_t)(n0 + srow) * D_K + scol;
    const __hip_bfloat16* gB1 = gB0 + (size_t)16 * D_K;
    char* lA0 = (char*)lsA + wave * 32 * 64 + lane * 16;
    char* lA1 = lA0 + 16 * 64;
    char* lB0 = (char*)lsB + wave * 32 * 64 + lane * 16;
    char* lB1 = lB0 + 16 * 64;

    // Fragment read: row R = wm*64 + i*16 + fr; (R>>1)&3 == (fr>>1)&3 (i*16, wm*64 vanish mod 8)
    const int fr  = lane & 15;
    const int fq  = lane >> 4;
    const int fsw = (fr >> 1) & 3;
    const __hip_bfloat16* fA = lsA + (wm * 64 + fr) * 32 + (fq ^ fsw) * 8;
    const __hip_bfloat16* fB = lsB + (wn * 64 + fr) * 32 + (fq ^ fsw) * 8;

    f32x4 acc[4][4] = {};

    for (int k0 = 0; k0 < D_K; k0 += 32) {
        __syncthreads();               // LDS safe to overwrite
        async16(lA0, gA0); async16(lA1, gA1);
        async16(lB0, gB0); async16(lB1, gB1);
        gA0 += 32; gA1 += 32; gB0 += 32; gB1 += 32;
        __syncthreads();               // drains vmcnt -> staged data visible

        bf16x8 a[4], b[4];
        #pragma unroll
        for (int i = 0; i < 4; i++) a[i] = *(const bf16x8*)(fA + i * 16 * 32);
        #pragma unroll
        for (int j2 = 0; j2 < 4; j2++) b[j2] = *(const bf16x8*)(fB + j2 * 16 * 32);
        #pragma unroll
        for (int i = 0; i < 4; i++)
            #pragma unroll
            for (int j2 = 0; j2 < 4; j2++)
                acc[i][j2] = __builtin_amdgcn_mfma_f32_16x16x32_bf16(a[i], b[j2], acc[i][j2], 0, 0, 0);
    }

    // Epilogue: d2 = x2 + w2 - 2*cross; out = -s*sqrt(max(d2, eps))
    const float s = scales[0];
    const int colb = n0 + wn * 64 + fr;          // C/D: col = lane&15
    const int rowb = m0 + wm * 64 + fq * 4;      // C/D: row = (lane>>4)*4 + reg

    float xv[4][4];
    #pragma unroll
    for (int i = 0; i < 4; i++)
        #pragma unroll
        for (int r = 0; r < 4; r++)
            xv[i][r] = x2[rowb + i * 16 + r];

    #pragma unroll
    for (int j2 = 0; j2 < 4; j2++) {
        const int gn = colb + j2 * 16;
        const bool nok = (gn < C_COLS);
        const float w2v = nok ? w2[gn] : 0.f;
        #pragma unroll
        for (int i = 0; i < 4; i++) {
            const int gm = rowb + i * 16;
            #pragma unroll
            for (int r = 0; r < 4; r++) {
                float d2 = xv[i][r] + w2v - 2.0f * acc[i][j2][r];
                d2 = fmaxf(d2, EPS_D2);
                float val = -s * __builtin_sqrtf(d2);
                if (nok) out[(size_t)(gm + r) * C_COLS + gn] = val;
            }
        }
    }
}

extern "C" void kernel_launch(void* const* d_in, const int* in_sizes, int n_in,
                              void* d_out, int out_size, void* d_ws, size_t ws_size,
                              hipStream_t stream) {
    const float* x      = (const float*)d_in[0];
    const float* w      = (const float*)d_in[1];
    const float* scales = (const float*)d_in[2];
    float* out = (float*)d_out;

    char* ws = (char*)d_ws;
    __hip_bfloat16* xb = (__hip_bfloat16*)ws;                                  // 67,108,864 B
    __hip_bfloat16* wb = (__hip_bfloat16*)(ws + (size_t)B_ROWS * D_K * 2);     //  4,194,304 B
    float* x2 = (float*)(ws + (size_t)B_ROWS * D_K * 2 + (size_t)C_PAD * D_K * 2);
    float* w2 = x2 + B_ROWS;

    prep_kernel<<<dim3((B_ROWS + C_PAD) / 4), dim3(256), 0, stream>>>(x, w, xb, wb, x2, w2);
    dml_gemm<<<dim3(8, B_ROWS / 128), dim3(256), 0, stream>>>(xb, wb, x2, w2, scales, out);
}